// Round 1
// baseline (560.350 us; speedup 1.0000x reference)
//
#include <hip/hip_runtime.h>
#include <stdint.h>

// Problem shape (fixed by the reference): M = B*S = 8192, K = DIN = 4096, N = DOUT = 4096
#define MDIM 8192
#define KDIM 4096
#define NDIM 4096

typedef float f32x4 __attribute__((ext_vector_type(4)));
typedef __bf16 bf16x8 __attribute__((ext_vector_type(8)));
typedef short short8 __attribute__((ext_vector_type(8)));
typedef float fl4 __attribute__((ext_vector_type(4)));
typedef int i32x4 __attribute__((ext_vector_type(4)));

// fp32 -> bf16 bits, round-to-nearest-even (values here are small integers: exact <= 256)
__device__ __forceinline__ short f2bf_bits(float f) {
    unsigned int u = __float_as_uint(f);
    u += 0x7fffu + ((u >> 16) & 1u);
    return (short)(u >> 16);
}

// async global->LDS, 16B per lane; LDS dest is wave-uniform base + lane*16 (HW semantics)
__device__ __forceinline__ void gload_lds16(const void* g, void* l) {
    __builtin_amdgcn_global_load_lds(
        (__attribute__((address_space(1))) void*)(uintptr_t)g,
        (__attribute__((address_space(3))) void*)(uintptr_t)l,
        16, 0, 0);
}

// x fp32 [M,K] -> xq bf16-bits [M,K], xq = rintf(x / input_scale) (integer-valued)
__global__ void __launch_bounds__(256) quant_x_kernel(const float* __restrict__ x,
                                                      short* __restrict__ xq,
                                                      const float* __restrict__ p_is) {
    const float is = p_is[0];
    const int64_t i = ((int64_t)blockIdx.x * 256 + threadIdx.x) * 8;
    fl4 a = *(const fl4*)(x + i);
    fl4 b = *(const fl4*)(x + i + 4);
    short8 o;
    o[0] = f2bf_bits(rintf(a[0] / is));
    o[1] = f2bf_bits(rintf(a[1] / is));
    o[2] = f2bf_bits(rintf(a[2] / is));
    o[3] = f2bf_bits(rintf(a[3] / is));
    o[4] = f2bf_bits(rintf(b[0] / is));
    o[5] = f2bf_bits(rintf(b[1] / is));
    o[6] = f2bf_bits(rintf(b[2] / is));
    o[7] = f2bf_bits(rintf(b[3] / is));
    *(short8*)(xq + i) = o;
}

// weight int32 [N,K] -> bf16 bits [N,K] (values in [-127,127]: exact)
__global__ void __launch_bounds__(256) quant_w_kernel(const int* __restrict__ w,
                                                      short* __restrict__ wq) {
    const int64_t i = ((int64_t)blockIdx.x * 256 + threadIdx.x) * 8;
    i32x4 a = *(const i32x4*)(w + i);
    i32x4 b = *(const i32x4*)(w + i + 4);
    short8 o;
    o[0] = f2bf_bits((float)a[0]);
    o[1] = f2bf_bits((float)a[1]);
    o[2] = f2bf_bits((float)a[2]);
    o[3] = f2bf_bits((float)a[3]);
    o[4] = f2bf_bits((float)b[0]);
    o[5] = f2bf_bits((float)b[1]);
    o[6] = f2bf_bits((float)b[2]);
    o[7] = f2bf_bits((float)b[3]);
    *(short8*)(wq + i) = o;
}

// NT GEMM: C[m,n] = sum_k A[m,k]*B[n,k], A=[M,K] bf16, B=[N,K] bf16, fused int8-requant epilogue.
// m97 structure: 128x128 tile, BK=32, 4 waves 2x2, 4x4 x mfma_f32_16x16x32_bf16 per wave,
// global_load_lds width=16 staging, 2-barrier K-loop.
__global__ void __launch_bounds__(256) gemm_bf16_kernel(
    const short* __restrict__ A,     // [MDIM][KDIM] bf16 bits
    const short* __restrict__ Bw,    // [NDIM][KDIM] bf16 bits
    const int* __restrict__ bias,    // [NDIM]
    const float* __restrict__ wscale,// [NDIM]
    const float* __restrict__ p_is,
    const float* __restrict__ p_os,
    int* __restrict__ out) {         // [MDIM][NDIM] int32
    __shared__ __align__(16) short As[128 * 32];
    __shared__ __align__(16) short Bs[128 * 32];

    const int tid  = threadIdx.x;
    const int lane = tid & 63;
    const int wave = tid >> 6;
    const int quad = lane >> 4;
    const int r16  = lane & 15;

    const int n0 = blockIdx.x * 128;   // x fastest over N: consecutive blocks share A-slice in L2/L3
    const int m0 = blockIdx.y * 128;

    const int wm = (wave & 1) * 64;
    const int wn = (wave >> 1) * 64;

    // staging: thread tid fetches 8 contiguous bf16 (16B); LDS layout row-major [128][32], no pad
    const int srow = tid >> 2;          // 0..63
    const int scol = (tid & 3) * 8;     // 0,8,16,24
    const short* gA0 = A  + (int64_t)(m0 + srow) * KDIM + scol;
    const short* gB0 = Bw + (int64_t)(n0 + srow) * KDIM + scol;

    short* lA0 = As + wave * 512;          // + lane*8 elts added by HW
    short* lA1 = As + 2048 + wave * 512;   // rows 64..127
    short* lB0 = Bs + wave * 512;
    short* lB1 = Bs + 2048 + wave * 512;

    f32x4 acc[4][4];
#pragma unroll
    for (int i = 0; i < 4; ++i)
#pragma unroll
        for (int j = 0; j < 4; ++j) acc[i][j] = (f32x4)0.0f;

    for (int k0 = 0; k0 < KDIM; k0 += 32) {
        __syncthreads();                       // prev tile's ds_reads done before overwrite
        gload_lds16(gA0 + k0, lA0);
        gload_lds16(gA0 + k0 + 64 * KDIM, lA1);
        gload_lds16(gB0 + k0, lB0);
        gload_lds16(gB0 + k0 + 64 * KDIM, lB1);
        __syncthreads();                       // vmcnt(0) drain before reads

        bf16x8 af[4], bfr[4];
#pragma unroll
        for (int mi = 0; mi < 4; ++mi)
            af[mi] = *(const bf16x8*)(As + (wm + mi * 16 + r16) * 32 + quad * 8);
#pragma unroll
        for (int ni = 0; ni < 4; ++ni)
            bfr[ni] = *(const bf16x8*)(Bs + (wn + ni * 16 + r16) * 32 + quad * 8);

#pragma unroll
        for (int mi = 0; mi < 4; ++mi)
#pragma unroll
            for (int ni = 0; ni < 4; ++ni)
                acc[mi][ni] = __builtin_amdgcn_mfma_f32_16x16x32_bf16(
                    af[mi], bfr[ni], acc[mi][ni], 0, 0, 0);
    }

    // epilogue: out = round((is*ws[n]*acc + bias[n]) / os)
    const float is = p_is[0];
    const float inv_os = 1.0f / p_os[0];

    float alpha[4], beta[4];
#pragma unroll
    for (int ni = 0; ni < 4; ++ni) {
        const int col = n0 + wn + ni * 16 + r16;
        alpha[ni] = is * wscale[col] * inv_os;
        beta[ni]  = (float)bias[col] * inv_os;
    }

    // C/D layout (verified m89/m91): col = lane&15, row = quad*4 + reg
#pragma unroll
    for (int mi = 0; mi < 4; ++mi) {
        const int row0 = m0 + wm + mi * 16 + quad * 4;
#pragma unroll
        for (int ni = 0; ni < 4; ++ni) {
            const int col = n0 + wn + ni * 16 + r16;
#pragma unroll
            for (int reg = 0; reg < 4; ++reg) {
                const float v = acc[mi][ni][reg] * alpha[ni] + beta[ni];
                out[(int64_t)(row0 + reg) * NDIM + col] = __float2int_rn(v);
            }
        }
    }
}

extern "C" void kernel_launch(void* const* d_in, const int* in_sizes, int n_in,
                              void* d_out, int out_size, void* d_ws, size_t ws_size,
                              hipStream_t stream) {
    (void)in_sizes; (void)n_in; (void)out_size; (void)ws_size;
    const float* x      = (const float*)d_in[0];
    const int*   weight = (const int*)d_in[1];
    const int*   bias   = (const int*)d_in[2];
    const float* wscale = (const float*)d_in[3];
    const float* p_is   = (const float*)d_in[4];
    const float* p_os   = (const float*)d_in[5];

    // workspace: xq bf16 [M,K] (64 MiB) + wq bf16 [N,K] (32 MiB) = 96 MiB
    short* xq = (short*)d_ws;
    short* wq = xq + (size_t)MDIM * KDIM;

    quant_x_kernel<<<(int)(((int64_t)MDIM * KDIM) / 2048), 256, 0, stream>>>(x, xq, p_is);
    quant_w_kernel<<<(int)(((int64_t)NDIM * KDIM) / 2048), 256, 0, stream>>>(weight, wq);

    dim3 grid(NDIM / 128, MDIM / 128);
    gemm_bf16_kernel<<<grid, 256, 0, stream>>>(xq, wq, bias, wscale, p_is, p_os, (int*)d_out);
}

// Round 2
// 559.857 us; speedup vs baseline: 1.0009x; 1.0009x over previous
//
#include <hip/hip_runtime.h>
#include <stdint.h>

// Problem shape (fixed by the reference): M = B*S = 8192, K = DIN = 4096, N = DOUT = 4096
#define MDIM 8192
#define KDIM 4096
#define NDIM 4096

typedef float f32x4 __attribute__((ext_vector_type(4)));
typedef __bf16 bf16x8 __attribute__((ext_vector_type(8)));
typedef short short8 __attribute__((ext_vector_type(8)));
typedef float fl4 __attribute__((ext_vector_type(4)));
typedef int i32x4 __attribute__((ext_vector_type(4)));

// fp32 -> bf16 bits, round-to-nearest-even (values here are small integers: exact <= 256)
__device__ __forceinline__ short f2bf_bits(float f) {
    unsigned int u = __float_as_uint(f);
    u += 0x7fffu + ((u >> 16) & 1u);
    return (short)(u >> 16);
}

// async global->LDS, 16B per lane; LDS dest is wave-uniform base + lane*16 (HW semantics)
__device__ __forceinline__ void gload_lds16(const void* g, void* l) {
    __builtin_amdgcn_global_load_lds(
        (__attribute__((address_space(1))) void*)(uintptr_t)g,
        (__attribute__((address_space(3))) void*)(uintptr_t)l,
        16, 0, 0);
}

// x fp32 [M,K] -> xq bf16-bits [M,K], xq = rintf(x * (1/input_scale)) (integer-valued)
// One reciprocal per thread instead of 8 IEEE divides.
__global__ void __launch_bounds__(256) quant_x_kernel(const float* __restrict__ x,
                                                      short* __restrict__ xq,
                                                      const float* __restrict__ p_is) {
    const float inv_is = 1.0f / p_is[0];
    const int64_t i = ((int64_t)blockIdx.x * 256 + threadIdx.x) * 8;
    fl4 a = *(const fl4*)(x + i);
    fl4 b = *(const fl4*)(x + i + 4);
    short8 o;
    o[0] = f2bf_bits(rintf(a[0] * inv_is));
    o[1] = f2bf_bits(rintf(a[1] * inv_is));
    o[2] = f2bf_bits(rintf(a[2] * inv_is));
    o[3] = f2bf_bits(rintf(a[3] * inv_is));
    o[4] = f2bf_bits(rintf(b[0] * inv_is));
    o[5] = f2bf_bits(rintf(b[1] * inv_is));
    o[6] = f2bf_bits(rintf(b[2] * inv_is));
    o[7] = f2bf_bits(rintf(b[3] * inv_is));
    *(short8*)(xq + i) = o;
}

// weight int32 [N,K] -> bf16 bits [N,K] (values in [-127,127]: exact)
__global__ void __launch_bounds__(256) quant_w_kernel(const int* __restrict__ w,
                                                      short* __restrict__ wq) {
    const int64_t i = ((int64_t)blockIdx.x * 256 + threadIdx.x) * 8;
    i32x4 a = *(const i32x4*)(w + i);
    i32x4 b = *(const i32x4*)(w + i + 4);
    short8 o;
    o[0] = f2bf_bits((float)a[0]);
    o[1] = f2bf_bits((float)a[1]);
    o[2] = f2bf_bits((float)a[2]);
    o[3] = f2bf_bits((float)a[3]);
    o[4] = f2bf_bits((float)b[0]);
    o[5] = f2bf_bits((float)b[1]);
    o[6] = f2bf_bits((float)b[2]);
    o[7] = f2bf_bits((float)b[3]);
    *(short8*)(wq + i) = o;
}

// NT GEMM: C[m,n] = sum_k A[m,k]*B[n,k], fused int8-requant epilogue.
// m97 structure: 128x128 tile, BK=32, 4 waves 2x2, 4x4 x mfma_f32_16x16x32_bf16 per wave,
// global_load_lds width=16 staging, 2-barrier K-loop.
//
// LDS bank-conflict fix (R2): XOR swizzle. Logical 16B chunk c of row r is stored at
// physical slot c ^ ((r>>1)&3). Implemented on the *global fetch* side (we choose which
// chunk each lane fetches), so global_load_lds's lane-linear LDS write is untouched and
// global coalescing is preserved (the 4 lanes of a row permute chunks within one 64B line).
// Read side: lane (quad,r16) reads slot quad ^ ((r16>>1)&3). Per 16-lane phase this covers
// every 4-bank group exactly twice -> 2-way aliasing, which is free (m136).
__global__ void __launch_bounds__(256) gemm_bf16_kernel(
    const short* __restrict__ A,     // [MDIM][KDIM] bf16 bits
    const short* __restrict__ Bw,    // [NDIM][KDIM] bf16 bits
    const int* __restrict__ bias,    // [NDIM]
    const float* __restrict__ wscale,// [NDIM]
    const float* __restrict__ p_is,
    const float* __restrict__ p_os,
    int* __restrict__ out) {         // [MDIM][NDIM] int32
    __shared__ __align__(16) short As[128 * 32];
    __shared__ __align__(16) short Bs[128 * 32];

    const int tid  = threadIdx.x;
    const int lane = tid & 63;
    const int wave = tid >> 6;
    const int quad = lane >> 4;
    const int r16  = lane & 15;
    const int rsw  = (r16 >> 1) & 3;   // read-side swizzle selector

    const int n0 = blockIdx.x * 128;   // x fastest over N: consecutive blocks share A-slice in L2/L3
    const int m0 = blockIdx.y * 128;

    const int wm = (wave & 1) * 64;
    const int wn = (wave >> 1) * 64;

    // staging: thread tid fetches 8 contiguous bf16 (16B) of logical chunk schunk of row srow
    const int srow   = tid >> 2;                      // 0..63
    const int schunk = (tid & 3) ^ ((srow >> 1) & 3); // XOR swizzle (write side)
    const short* gA0 = A  + (int64_t)(m0 + srow) * KDIM + schunk * 8;
    const short* gB0 = Bw + (int64_t)(n0 + srow) * KDIM + schunk * 8;

    short* lA0 = As + wave * 512;          // + lane*8 elts added by HW
    short* lA1 = As + 2048 + wave * 512;   // rows 64..127 (row-64 has same swizzle: 32 ≡ 0 mod 4)
    short* lB0 = Bs + wave * 512;
    short* lB1 = Bs + 2048 + wave * 512;

    f32x4 acc[4][4];
#pragma unroll
    for (int i = 0; i < 4; ++i)
#pragma unroll
        for (int j = 0; j < 4; ++j) acc[i][j] = (f32x4)0.0f;

    for (int k0 = 0; k0 < KDIM; k0 += 32) {
        __syncthreads();                       // prev tile's ds_reads done before overwrite
        gload_lds16(gA0 + k0, lA0);
        gload_lds16(gA0 + k0 + 64 * KDIM, lA1);
        gload_lds16(gB0 + k0, lB0);
        gload_lds16(gB0 + k0 + 64 * KDIM, lB1);
        __syncthreads();                       // vmcnt(0) drain before reads

        bf16x8 af[4], bfr[4];
#pragma unroll
        for (int mi = 0; mi < 4; ++mi)
            af[mi] = *(const bf16x8*)(As + (wm + mi * 16 + r16) * 32 + (quad ^ rsw) * 8);
#pragma unroll
        for (int ni = 0; ni < 4; ++ni)
            bfr[ni] = *(const bf16x8*)(Bs + (wn + ni * 16 + r16) * 32 + (quad ^ rsw) * 8);

#pragma unroll
        for (int mi = 0; mi < 4; ++mi)
#pragma unroll
            for (int ni = 0; ni < 4; ++ni)
                acc[mi][ni] = __builtin_amdgcn_mfma_f32_16x16x32_bf16(
                    af[mi], bfr[ni], acc[mi][ni], 0, 0, 0);
    }

    // epilogue: out = round((is*ws[n]*acc + bias[n]) / os)
    const float is = p_is[0];
    const float inv_os = 1.0f / p_os[0];

    float alpha[4], beta[4];
#pragma unroll
    for (int ni = 0; ni < 4; ++ni) {
        const int col = n0 + wn + ni * 16 + r16;
        alpha[ni] = is * wscale[col] * inv_os;
        beta[ni]  = (float)bias[col] * inv_os;
    }

    // C/D layout (verified m89/m91): col = lane&15, row = quad*4 + reg
#pragma unroll
    for (int mi = 0; mi < 4; ++mi) {
        const int row0 = m0 + wm + mi * 16 + quad * 4;
#pragma unroll
        for (int ni = 0; ni < 4; ++ni) {
            const int col = n0 + wn + ni * 16 + r16;
#pragma unroll
            for (int reg = 0; reg < 4; ++reg) {
                const float v = acc[mi][ni][reg] * alpha[ni] + beta[ni];
                out[(int64_t)(row0 + reg) * NDIM + col] = __float2int_rn(v);
            }
        }
    }
}

extern "C" void kernel_launch(void* const* d_in, const int* in_sizes, int n_in,
                              void* d_out, int out_size, void* d_ws, size_t ws_size,
                              hipStream_t stream) {
    (void)in_sizes; (void)n_in; (void)out_size; (void)ws_size;
    const float* x      = (const float*)d_in[0];
    const int*   weight = (const int*)d_in[1];
    const int*   bias   = (const int*)d_in[2];
    const float* wscale = (const float*)d_in[3];
    const float* p_is   = (const float*)d_in[4];
    const float* p_os   = (const float*)d_in[5];

    // workspace: xq bf16 [M,K] (64 MiB) + wq bf16 [N,K] (32 MiB) = 96 MiB
    short* xq = (short*)d_ws;
    short* wq = xq + (size_t)MDIM * KDIM;

    quant_x_kernel<<<(int)(((int64_t)MDIM * KDIM) / 2048), 256, 0, stream>>>(x, xq, p_is);
    quant_w_kernel<<<(int)(((int64_t)NDIM * KDIM) / 2048), 256, 0, stream>>>(weight, wq);

    dim3 grid(NDIM / 128, MDIM / 128);
    gemm_bf16_kernel<<<grid, 256, 0, stream>>>(xq, wq, bias, wscale, p_is, p_os, (int*)d_out);
}

// Round 3
// 555.002 us; speedup vs baseline: 1.0096x; 1.0087x over previous
//
#include <hip/hip_runtime.h>
#include <stdint.h>

// Problem shape (fixed by the reference): M = B*S = 8192, K = DIN = 4096, N = DOUT = 4096
#define MDIM 8192
#define KDIM 4096
#define NDIM 4096

typedef float f32x4 __attribute__((ext_vector_type(4)));
typedef __bf16 bf16x8 __attribute__((ext_vector_type(8)));
typedef short short8 __attribute__((ext_vector_type(8)));
typedef float fl4 __attribute__((ext_vector_type(4)));
typedef int i32x4 __attribute__((ext_vector_type(4)));

// fp32 -> bf16 bits, round-to-nearest-even (values here are small integers: exact <= 256)
__device__ __forceinline__ short f2bf_bits(float f) {
    unsigned int u = __float_as_uint(f);
    u += 0x7fffu + ((u >> 16) & 1u);
    return (short)(u >> 16);
}

// async global->LDS, 16B per lane; LDS dest is wave-uniform base + lane*16 (HW semantics)
__device__ __forceinline__ void gload_lds16(const void* g, void* l) {
    __builtin_amdgcn_global_load_lds(
        (__attribute__((address_space(1))) void*)(uintptr_t)g,
        (__attribute__((address_space(3))) void*)(uintptr_t)l,
        16, 0, 0);
}

// x fp32 [M,K] -> xq bf16-bits [M,K], xq = rintf(x * (1/input_scale)) (integer-valued)
// NT loads: x is read exactly once -- don't pollute L2/L3 (we want xq/wq to stay resident for gemm).
__global__ void __launch_bounds__(256) quant_x_kernel(const float* __restrict__ x,
                                                      short* __restrict__ xq,
                                                      const float* __restrict__ p_is) {
    const float inv_is = 1.0f / p_is[0];
    const int64_t i = ((int64_t)blockIdx.x * 256 + threadIdx.x) * 8;
    fl4 a = __builtin_nontemporal_load((const fl4*)(x + i));
    fl4 b = __builtin_nontemporal_load((const fl4*)(x + i + 4));
    short8 o;
    o[0] = f2bf_bits(rintf(a[0] * inv_is));
    o[1] = f2bf_bits(rintf(a[1] * inv_is));
    o[2] = f2bf_bits(rintf(a[2] * inv_is));
    o[3] = f2bf_bits(rintf(a[3] * inv_is));
    o[4] = f2bf_bits(rintf(b[0] * inv_is));
    o[5] = f2bf_bits(rintf(b[1] * inv_is));
    o[6] = f2bf_bits(rintf(b[2] * inv_is));
    o[7] = f2bf_bits(rintf(b[3] * inv_is));
    *(short8*)(xq + i) = o;   // normal store: gemm re-reads xq, let L3 keep it
}

// weight int32 [N,K] -> bf16 bits [N,K] (values in [-127,127]: exact)
__global__ void __launch_bounds__(256) quant_w_kernel(const int* __restrict__ w,
                                                      short* __restrict__ wq) {
    const int64_t i = ((int64_t)blockIdx.x * 256 + threadIdx.x) * 8;
    i32x4 a = __builtin_nontemporal_load((const i32x4*)(w + i));
    i32x4 b = __builtin_nontemporal_load((const i32x4*)(w + i + 4));
    short8 o;
    o[0] = f2bf_bits((float)a[0]);
    o[1] = f2bf_bits((float)a[1]);
    o[2] = f2bf_bits((float)a[2]);
    o[3] = f2bf_bits((float)a[3]);
    o[4] = f2bf_bits((float)b[0]);
    o[5] = f2bf_bits((float)b[1]);
    o[6] = f2bf_bits((float)b[2]);
    o[7] = f2bf_bits((float)b[3]);
    *(short8*)(wq + i) = o;   // normal store: gemm re-reads wq
}

// NT GEMM: C[m,n] = sum_k A[m,k]*B[n,k], fused int8-requant epilogue.
// m97 structure: 128x128 tile, BK=32, 4 waves 2x2, 4x4 x mfma_f32_16x16x32_bf16 per wave,
// global_load_lds width=16 staging, 2-barrier K-loop, XOR-swizzled LDS (R2: conflicts = 0).
//
// R3: 16x16 supertile block swizzle. Dispatch is bid-ordered; remap so each group of 256
// consecutive bids covers a 16(m) x 16(n) square of tiles -> concurrent working set
// 16.8 MB A + 16.8 MB B (~ aggregate L2) instead of 8 MB A + ALL 33.5 MB B.
// Predicted: FETCH_SIZE 326 MB -> ~120-180 MB.
// Out stores are nontemporal: written once, never re-read -- keep cache space for tiles.
__global__ void __launch_bounds__(256) gemm_bf16_kernel(
    const short* __restrict__ A,     // [MDIM][KDIM] bf16 bits
    const short* __restrict__ Bw,    // [NDIM][KDIM] bf16 bits
    const int* __restrict__ bias,    // [NDIM]
    const float* __restrict__ wscale,// [NDIM]
    const float* __restrict__ p_is,
    const float* __restrict__ p_os,
    int* __restrict__ out) {         // [MDIM][NDIM] int32
    __shared__ __align__(16) short As[128 * 32];
    __shared__ __align__(16) short Bs[128 * 32];

    const int tid  = threadIdx.x;
    const int lane = tid & 63;
    const int wave = tid >> 6;
    const int quad = lane >> 4;
    const int r16  = lane & 15;
    const int rsw  = (r16 >> 1) & 3;   // read-side swizzle selector

    // 16x16 supertile remap (bijective over the 32x64 grid):
    //   g = bid>>8 (8 groups); n_blk = (g&1)*16 + (bid&15); m_blk = (g>>1)*16 + ((bid>>4)&15)
    const int bid   = blockIdx.y * gridDim.x + blockIdx.x;  // gridDim.x = 32
    const int g     = bid >> 8;
    const int n_blk = (g & 1) * 16 + (bid & 15);
    const int m_blk = (g >> 1) * 16 + ((bid >> 4) & 15);
    const int n0 = n_blk * 128;
    const int m0 = m_blk * 128;

    const int wm = (wave & 1) * 64;
    const int wn = (wave >> 1) * 64;

    // staging: thread tid fetches 8 contiguous bf16 (16B) of logical chunk schunk of row srow
    const int srow   = tid >> 2;                      // 0..63
    const int schunk = (tid & 3) ^ ((srow >> 1) & 3); // XOR swizzle (write side)
    const short* gA0 = A  + (int64_t)(m0 + srow) * KDIM + schunk * 8;
    const short* gB0 = Bw + (int64_t)(n0 + srow) * KDIM + schunk * 8;

    short* lA0 = As + wave * 512;          // + lane*8 elts added by HW
    short* lA1 = As + 2048 + wave * 512;   // rows 64..127 (same swizzle phase: 64 ≡ 0 mod 4)
    short* lB0 = Bs + wave * 512;
    short* lB1 = Bs + 2048 + wave * 512;

    f32x4 acc[4][4];
#pragma unroll
    for (int i = 0; i < 4; ++i)
#pragma unroll
        for (int j = 0; j < 4; ++j) acc[i][j] = (f32x4)0.0f;

    for (int k0 = 0; k0 < KDIM; k0 += 32) {
        __syncthreads();                       // prev tile's ds_reads done before overwrite
        gload_lds16(gA0 + k0, lA0);
        gload_lds16(gA0 + k0 + 64 * KDIM, lA1);
        gload_lds16(gB0 + k0, lB0);
        gload_lds16(gB0 + k0 + 64 * KDIM, lB1);
        __syncthreads();                       // vmcnt(0) drain before reads

        bf16x8 af[4], bfr[4];
#pragma unroll
        for (int mi = 0; mi < 4; ++mi)
            af[mi] = *(const bf16x8*)(As + (wm + mi * 16 + r16) * 32 + (quad ^ rsw) * 8);
#pragma unroll
        for (int ni = 0; ni < 4; ++ni)
            bfr[ni] = *(const bf16x8*)(Bs + (wn + ni * 16 + r16) * 32 + (quad ^ rsw) * 8);

#pragma unroll
        for (int mi = 0; mi < 4; ++mi)
#pragma unroll
            for (int ni = 0; ni < 4; ++ni)
                acc[mi][ni] = __builtin_amdgcn_mfma_f32_16x16x32_bf16(
                    af[mi], bfr[ni], acc[mi][ni], 0, 0, 0);
    }

    // epilogue: out = round((is*ws[n]*acc + bias[n]) / os)
    const float is = p_is[0];
    const float inv_os = 1.0f / p_os[0];

    float alpha[4], beta[4];
#pragma unroll
    for (int ni = 0; ni < 4; ++ni) {
        const int col = n0 + wn + ni * 16 + r16;
        alpha[ni] = is * wscale[col] * inv_os;
        beta[ni]  = (float)bias[col] * inv_os;
    }

    // C/D layout (verified m89/m91): col = lane&15, row = quad*4 + reg
#pragma unroll
    for (int mi = 0; mi < 4; ++mi) {
        const int row0 = m0 + wm + mi * 16 + quad * 4;
#pragma unroll
        for (int ni = 0; ni < 4; ++ni) {
            const int col = n0 + wn + ni * 16 + r16;
#pragma unroll
            for (int reg = 0; reg < 4; ++reg) {
                const float v = acc[mi][ni][reg] * alpha[ni] + beta[ni];
                __builtin_nontemporal_store(__float2int_rn(v),
                                            out + (int64_t)(row0 + reg) * NDIM + col);
            }
        }
    }
}

extern "C" void kernel_launch(void* const* d_in, const int* in_sizes, int n_in,
                              void* d_out, int out_size, void* d_ws, size_t ws_size,
                              hipStream_t stream) {
    (void)in_sizes; (void)n_in; (void)out_size; (void)ws_size;
    const float* x      = (const float*)d_in[0];
    const int*   weight = (const int*)d_in[1];
    const int*   bias   = (const int*)d_in[2];
    const float* wscale = (const float*)d_in[3];
    const float* p_is   = (const float*)d_in[4];
    const float* p_os   = (const float*)d_in[5];

    // workspace: xq bf16 [M,K] (64 MiB) + wq bf16 [N,K] (32 MiB) = 96 MiB
    short* xq = (short*)d_ws;
    short* wq = xq + (size_t)MDIM * KDIM;

    quant_x_kernel<<<(int)(((int64_t)MDIM * KDIM) / 2048), 256, 0, stream>>>(x, xq, p_is);
    quant_w_kernel<<<(int)(((int64_t)NDIM * KDIM) / 2048), 256, 0, stream>>>(weight, wq);

    dim3 grid(NDIM / 128, MDIM / 128);
    gemm_bf16_kernel<<<grid, 256, 0, stream>>>(xq, wq, bias, wscale, p_is, p_os, (int*)d_out);
}